// Round 9
// baseline (2755.316 us; speedup 1.0000x reference)
//
#include <hip/hip_runtime.h>
#include <hip/hip_bf16.h>

// QLSTM: T=512, B=64, D=256, H=512, NQ=64
// out = stacked[T,B,H] fp32, hT[B,H], cT[B,H]
//
// Fused weights Kh=[Wh@M]x4 [512,2048] bf16, Kx=[Wx@M]x4 [256,2048] bf16,
// bias=[b@M+mb] [2048] f32; persistent cooperative kernel (32 blocks x 256
// thr). DATA-EMBEDDED SYNC (R5, proven): consumers poll the h data lines
// (bf16 sentinel 0x7FC0) with sc0+sc1 MALL-coherent loads; producers write
// 8B atomic sc0+sc1 stores; 4-buffer rotation with re-poisoning.
// R9 (single change vs R5): MASKED-RETRY poll -- the initial sweep loads all
// 16 chunks; retries reload ONLY chunks still showing sentinel (wave-uniform
// mask). Cuts MALL poll congestion ~10x (R5 FETCH_SIZE showed ~11 full
// sweeps/step). Kh stays in LDS (register-Kh caused launch failure, R7/R8).

#define NBLK 32
#define SENT16 ((short)0x7FC0)

typedef __attribute__((ext_vector_type(8))) short s16x8;
typedef __attribute__((ext_vector_type(4))) float f32x4;

static __device__ __forceinline__ unsigned short f2bf(float f) {
    union { float f; unsigned int u; } v; v.f = f;
    return (unsigned short)((v.u + 0x7FFFu + ((v.u >> 16) & 1u)) >> 16);
}
static __device__ __forceinline__ float sigmoid_f(float x) {
    x = fminf(fmaxf(x, -30.f), 30.f);
    float e = __expf(-x);
    return __builtin_amdgcn_rcpf(1.f + e);
}
static __device__ __forceinline__ float tanh_f(float x) {
    x = fminf(fmaxf(x, -15.f), 15.f);
    float e = __expf(2.f * x);
    return 1.f - 2.f * __builtin_amdgcn_rcpf(1.f + e);
}

// ---------------- prep: fused weights + bias + x->bf16 + hbuf init ----------
__global__ __launch_bounds__(256) void prep_kernel(
    const float* __restrict__ x,
    const float* __restrict__ Wf, const float* __restrict__ bf_,
    const float* __restrict__ Wi, const float* __restrict__ bi_,
    const float* __restrict__ Wg, const float* __restrict__ bg_,
    const float* __restrict__ Wo, const float* __restrict__ bo_,
    const float* __restrict__ Mf, const float* __restrict__ mbf_,
    const float* __restrict__ Mi, const float* __restrict__ mbi_,
    const float* __restrict__ Mg, const float* __restrict__ mbg_,
    const float* __restrict__ Mo, const float* __restrict__ mbo_,
    unsigned short* __restrict__ Khp,   // packed [32][4][16][64][8] bf16
    unsigned short* __restrict__ Kxp,   // packed [32][4][8][64][8]  bf16
    float* __restrict__ bias_out,       // [2048]
    unsigned short* __restrict__ xbf,   // [512*64*256] bf16
    unsigned short* __restrict__ hb)    // [4][64*512]: buf0=0, buf1..3=sentinel
{
    const float* Ws[4] = {Wf, Wi, Wg, Wo};
    const float* Ms[4] = {Mf, Mi, Mg, Mo};
    const float* bs[4] = {bf_, bi_, bg_, bo_};
    const float* mbs[4] = {mbf_, mbi_, mbg_, mbo_};
    const long long NKH = 512LL * 2048;
    const long long NKX = 256LL * 2048;
    const long long NB_ = 2048;
    const long long NX = 512LL * 64 * 256;
    const long long NHB = 4LL * 32768;
    const long long total = NKH + NKX + NB_ + NX + NHB;
    for (long long id = (long long)blockIdx.x * blockDim.x + threadIdx.x; id < total;
         id += (long long)gridDim.x * blockDim.x) {
        if (id < NKH) {
            int i = (int)id;
            int k = i >> 11, scol = i & 2047;
            int n = scol >> 9, c = scol & 511;
            const float* W = Ws[n]; const float* M = Ms[n];
            float acc = 0.f;
            #pragma unroll 8
            for (int q = 0; q < 64; ++q) acc = fmaf(W[(256 + k) * 64 + q], M[q * 512 + c], acc);
            int blk = c >> 4, jj = c & 15, kc = k >> 5;
            int l = (((k >> 3) & 3) << 4) | jj, j = k & 7;
            Khp[((((blk * 4 + n) * 16 + kc) * 64 + l) << 3) + j] = f2bf(acc);
        } else if (id < NKH + NKX) {
            int i = (int)(id - NKH);
            int k = i >> 11, scol = i & 2047;
            int n = scol >> 9, c = scol & 511;
            const float* W = Ws[n]; const float* M = Ms[n];
            float acc = 0.f;
            #pragma unroll 8
            for (int q = 0; q < 64; ++q) acc = fmaf(W[k * 64 + q], M[q * 512 + c], acc);
            int blk = c >> 4, jj = c & 15, kc = k >> 5;
            int l = (((k >> 3) & 3) << 4) | jj, j = k & 7;
            Kxp[((((blk * 4 + n) * 8 + kc) * 64 + l) << 3) + j] = f2bf(acc);
        } else if (id < NKH + NKX + NB_) {
            int scol = (int)(id - NKH - NKX);
            int n = scol >> 9, c = scol & 511;
            const float* M = Ms[n];
            float acc = mbs[n][c];
            #pragma unroll 8
            for (int q = 0; q < 64; ++q) acc = fmaf(bs[n][q], M[q * 512 + c], acc);
            bias_out[scol] = acc;
        } else if (id < NKH + NKX + NB_ + NX) {
            long long e = id - NKH - NKX - NB_;
            xbf[e] = f2bf(x[e]);
        } else {
            int e = (int)(id - NKH - NKX - NB_ - NX);
            hb[e] = (e < 32768) ? (unsigned short)0 : (unsigned short)0x7FC0;
        }
    }
}

// h chunk load: MALL-coherent (bypass L1+L2); early-clobber dest so the
// output can never alias the shared address register hr
#define HLOAD(i, off_) \
    asm volatile("global_load_dwordx4 %0, %1, off offset:" #off_ " sc0 sc1" \
                 : "=&v"(hfrag[i]) : "v"(hr))
#define RETRY(i, off_) if (msk & (1u << i)) { HLOAD(i, off_); }
#define CHK1(i) if (__any((hfrag[i][0] == SENT16) | (hfrag[i][4] == SENT16))) msk |= 1u << i;
#define CHK2(i) if ((msk & (1u << i)) && \
                    __any((hfrag[i][0] == SENT16) | (hfrag[i][4] == SENT16))) nm |= 1u << i;

// ---------------- persistent recurrence kernel ----------------
// 32 blocks x 256 threads. Block s owns h-cols [s*16, s*16+16).
// Wave w handles batch rows [w*16, w*16+16): independent sync domain.
__global__ __launch_bounds__(256, 1) void qlstm_persist(
    const unsigned short* __restrict__ xbf,
    const unsigned short* __restrict__ Khp,
    const unsigned short* __restrict__ Kxp,
    const float* __restrict__ bias,
    float* __restrict__ out,
    unsigned short* hbuf)        // [4][64*512] bf16 rotation
{
    extern __shared__ unsigned short smem[];
    unsigned short* lKh = smem;           // [4][16][64][8] = 64 KB
    unsigned short* lKx = smem + 32768;   // [4][8][64][8]  = 32 KB
    const int tid = threadIdx.x, slot = blockIdx.x;
    const int lane = tid & 63, w = tid >> 6;

    // stage K slices into LDS (once)
    {
        const uint4* src = (const uint4*)(Khp + (size_t)slot * 32768);
        uint4* dst = (uint4*)lKh;
        for (int i = tid; i < 4096; i += 256) dst[i] = src[i];
        const uint4* src2 = (const uint4*)(Kxp + (size_t)slot * 16384);
        uint4* dst2 = (uint4*)lKx;
        for (int i = tid; i < 2048; i += 256) dst2[i] = src2[i];
    }
    __syncthreads();

    const int jj = lane & 15, lhi = lane >> 4;
    const int hcol = slot * 16 + jj;
    const int row0 = w * 16;
    const int browbase = row0 + lhi * 4;

    float bias_v[4];
    #pragma unroll
    for (int n = 0; n < 4; ++n) bias_v[n] = bias[n * 512 + hcol];
    float c_state[4] = {0.f, 0.f, 0.f, 0.f};

    // x fragments for t=0
    s16x8 xfrag[8];
    {
        const unsigned short* xr = xbf + (long long)(row0 + jj) * 256 + lhi * 8;
        #pragma unroll
        for (int kc = 0; kc < 8; ++kc) xfrag[kc] = *(const s16x8*)(xr + kc * 32);
    }

    for (int t = 0; t < 512; ++t) {
        const unsigned short* hcur = hbuf + (t & 3) * 32768;
        unsigned short* hnext = hbuf + ((t + 1) & 3) * 32768;
        unsigned short* hpois = hbuf + ((t + 3) & 3) * 32768;   // == (t-1) mod 4

        // ---- x part (independent of h): acc = bias + x_t @ Kx (Kx from LDS) ----
        f32x4 acc[4];
        #pragma unroll
        for (int n = 0; n < 4; ++n) {
            f32x4 b0 = {bias_v[n], bias_v[n], bias_v[n], bias_v[n]};
            acc[n] = b0;
        }
        #pragma unroll
        for (int kc = 0; kc < 8; ++kc) {
            #pragma unroll
            for (int n = 0; n < 4; ++n) {
                s16x8 b = *(const s16x8*)(lKx + (((n * 8 + kc) * 64 + lane) << 3));
                acc[n] = __builtin_amdgcn_mfma_f32_16x16x32_bf16(xfrag[kc], b, acc[n], 0, 0, 0);
            }
        }

        // prefetch next step's x fragments (plain cached; completes under poll)
        if (t < 511) {
            const unsigned short* xr = xbf + ((long long)(t + 1) * 64 + row0 + jj) * 256 + lhi * 8;
            #pragma unroll
            for (int kc = 0; kc < 8; ++kc) xfrag[kc] = *(const s16x8*)(xr + kc * 32);
        }

        // ---- poll directly on h data; retries reload ONLY sentinel chunks ----
        s16x8 hfrag[16];
        const unsigned short* hr = hcur + (row0 + jj) * 512 + lhi * 8;
        HLOAD(0, 0);    HLOAD(1, 64);   HLOAD(2, 128);  HLOAD(3, 192);
        HLOAD(4, 256);  HLOAD(5, 320);  HLOAD(6, 384);  HLOAD(7, 448);
        HLOAD(8, 512);  HLOAD(9, 576);  HLOAD(10, 640); HLOAD(11, 704);
        HLOAD(12, 768); HLOAD(13, 832); HLOAD(14, 896); HLOAD(15, 960);
        asm volatile("s_waitcnt vmcnt(0)" ::: "memory");
        __builtin_amdgcn_sched_barrier(0);
        unsigned msk = 0;
        CHK1(0)  CHK1(1)  CHK1(2)  CHK1(3)  CHK1(4)  CHK1(5)  CHK1(6)  CHK1(7)
        CHK1(8)  CHK1(9)  CHK1(10) CHK1(11) CHK1(12) CHK1(13) CHK1(14) CHK1(15)
        int guard = 0;
        while (msk && ++guard < 16384) {
            RETRY(0, 0)    RETRY(1, 64)   RETRY(2, 128)  RETRY(3, 192)
            RETRY(4, 256)  RETRY(5, 320)  RETRY(6, 384)  RETRY(7, 448)
            RETRY(8, 512)  RETRY(9, 576)  RETRY(10, 640) RETRY(11, 704)
            RETRY(12, 768) RETRY(13, 832) RETRY(14, 896) RETRY(15, 960)
            asm volatile("s_waitcnt vmcnt(0)" ::: "memory");
            __builtin_amdgcn_sched_barrier(0);
            unsigned nm = 0;
            CHK2(0)  CHK2(1)  CHK2(2)  CHK2(3)  CHK2(4)  CHK2(5)  CHK2(6)  CHK2(7)
            CHK2(8)  CHK2(9)  CHK2(10) CHK2(11) CHK2(12) CHK2(13) CHK2(14) CHK2(15)
            msk = nm;
        }
        __builtin_amdgcn_sched_barrier(0);

        // ---- h part: acc += h(t) @ Kh (Kh from LDS, as in R5) ----
        #pragma unroll
        for (int kc = 0; kc < 16; ++kc) {
            #pragma unroll
            for (int n = 0; n < 4; ++n) {
                s16x8 b = *(const s16x8*)(lKh + (((n * 16 + kc) * 64 + lane) << 3));
                acc[n] = __builtin_amdgcn_mfma_f32_16x16x32_bf16(hfrag[kc], b, acc[n], 0, 0, 0);
            }
        }

        // ---- gates + state update; h data stores (atomic 8B, sc0 sc1) ----
        float hv[4], cv[4];
        #pragma unroll
        for (int r = 0; r < 4; ++r) {
            float fv = sigmoid_f(acc[0][r]);
            float iv = sigmoid_f(acc[1][r]);
            float gv = tanh_f(acc[2][r]);
            float ov = sigmoid_f(acc[3][r]);
            float c = fmaf(fv, c_state[r], iv * gv);
            c_state[r] = c;
            float h = ov * tanh_f(c);
            hv[r] = h; cv[r] = c;
            unsigned int myb = f2bf(h);
            unsigned int o1 = (unsigned int)__shfl_xor((int)myb, 1, 64);
            unsigned int b01 = (myb & 0xFFFFu) | (o1 << 16);            // even jj
            unsigned long long o2 =
                (unsigned long long)(unsigned int)__shfl_xor((int)b01, 2, 64);
            unsigned long long q = (unsigned long long)b01 | (o2 << 32); // jj%4==0
            if ((jj & 3) == 0) {
                unsigned long long* ha =
                    (unsigned long long*)(hnext + (browbase + r) * 512 + slot * 16 + jj);
                asm volatile("global_store_dwordx2 %0, %1, off sc0 sc1"
                             :: "v"(ha), "v"(q) : "memory");
            }
        }

        // ---- re-poison the buffer consumed at step t-1 (own write tile).
        // Poll success at t proves all wave-w peers finished reading it; next
        // data write to it is at t+2, and this store drains at the next poll.
        {
            unsigned long long s64 = 0x7FC07FC07FC07FC0ull;
            unsigned long long* pa = (unsigned long long*)
                (hpois + (row0 + (lane >> 2)) * 512 + slot * 16 + (lane & 3) * 4);
            asm volatile("global_store_dwordx2 %0, %1, off sc0 sc1"
                         :: "v"(pa), "v"(s64) : "memory");
        }

        // ---- out stores off the critical path (plain cached) ----
        float* outt = out + (long long)t * 32768;
        #pragma unroll
        for (int r = 0; r < 4; ++r) {
            const int brow = browbase + r;
            outt[brow * 512 + hcol] = hv[r];
            if (t == 511) {
                out[16777216 + brow * 512 + hcol] = hv[r];   // hT
                out[16809984 + brow * 512 + hcol] = cv[r];   // cT
            }
        }
    }
}

extern "C" void kernel_launch(void* const* d_in, const int* in_sizes, int n_in,
                              void* d_out, int out_size, void* d_ws, size_t ws_size,
                              hipStream_t stream) {
    const float* x   = (const float*)d_in[0];
    const float* Wf  = (const float*)d_in[1];  const float* bf_  = (const float*)d_in[2];
    const float* Wi  = (const float*)d_in[3];  const float* bi_  = (const float*)d_in[4];
    const float* Wg  = (const float*)d_in[5];  const float* bg_  = (const float*)d_in[6];
    const float* Wo  = (const float*)d_in[7];  const float* bo_  = (const float*)d_in[8];
    const float* Mf  = (const float*)d_in[9];  const float* mbf_ = (const float*)d_in[10];
    const float* Mi  = (const float*)d_in[11]; const float* mbi_ = (const float*)d_in[12];
    const float* Mg  = (const float*)d_in[13]; const float* mbg_ = (const float*)d_in[14];
    const float* Mo  = (const float*)d_in[15]; const float* mbo_ = (const float*)d_in[16];
    float* outp = (float*)d_out;

    char* ws = (char*)d_ws;
    unsigned short* xbf  = (unsigned short*)(ws);                    // 16,777,216 B
    unsigned short* Khp  = (unsigned short*)(ws + 16777216);         //  2,097,152 B
    unsigned short* Kxp  = (unsigned short*)(ws + 18874368);         //  1,048,576 B
    float*          bias = (float*)        (ws + 19922944);          //      8,192 B
    unsigned short* hbuf = (unsigned short*)(ws + 19931136);         //    262,144 B (4 bufs)
    if (ws_size < 20193280) return;

    // prep re-initializes ALL workspace state every call (graph-replay safe):
    // hbuf buf0 = h_0 = 0, buf1..3 = sentinel.
    prep_kernel<<<4096, 256, 0, stream>>>(
        x, Wf, bf_, Wi, bi_, Wg, bg_, Wo, bo_,
        Mf, mbf_, Mi, mbi_, Mg, mbg_, Mo, mbo_,
        Khp, Kxp, bias, xbf, hbuf);

    // 96 KB dynamic LDS
    hipFuncSetAttribute((const void*)qlstm_persist,
                        hipFuncAttributeMaxDynamicSharedMemorySize, 98304);

    const unsigned short* xbf_c = xbf;
    const unsigned short* Khp_c = Khp;
    const unsigned short* Kxp_c = Kxp;
    const float* bias_c = bias;
    float* out_c = outp;
    unsigned short* hbuf_c = hbuf;
    void* args[] = {(void*)&xbf_c, (void*)&Khp_c, (void*)&Kxp_c, (void*)&bias_c,
                    (void*)&out_c, (void*)&hbuf_c};
    hipLaunchCooperativeKernel((const void*)qlstm_persist, dim3(NBLK), dim3(256),
                               args, 98304, stream);
}

// Round 10
// 1887.143 us; speedup vs baseline: 1.4600x; 1.4600x over previous
//
#include <hip/hip_runtime.h>
#include <hip/hip_bf16.h>

// QLSTM: T=512, B=64, D=256, H=512, NQ=64
// out = stacked[T,B,H] fp32, hT[B,H], cT[B,H]
//
// Fused weights Kh=[Wh@M]x4 [512,2048] bf16, Kx=[Wx@M]x4 [256,2048] bf16,
// bias=[b@M+mb] [2048] f32; persistent cooperative kernel.
// DATA-EMBEDDED SYNC (R5, proven): consumers poll the h data lines (bf16
// sentinel 0x7FC0) with sc0+sc1 MALL-coherent loads; producers write 8B
// atomic sc0+sc1 stores; 4-buffer rotation with re-poisoning.
// R10 (geometry only; inner loop identical to R5): 128 blocks x 64 threads
// (ONE wave per block), 96KB LDS -> 1 block/CU. Block bid: domain w=bid>>5
// (batch rows [16w,16w+16)), slot=bid&31 (h-cols [slot*16,slot*16+16)).
// Each wave gets a private CU: private LDS pipe (96KB/step, was 4x96),
// private issue slots, no co-resident polling waves.

#define NBLK 32
#define SENT16 ((short)0x7FC0)

typedef __attribute__((ext_vector_type(8))) short s16x8;
typedef __attribute__((ext_vector_type(4))) float f32x4;

static __device__ __forceinline__ unsigned short f2bf(float f) {
    union { float f; unsigned int u; } v; v.f = f;
    return (unsigned short)((v.u + 0x7FFFu + ((v.u >> 16) & 1u)) >> 16);
}
static __device__ __forceinline__ float sigmoid_f(float x) {
    x = fminf(fmaxf(x, -30.f), 30.f);
    float e = __expf(-x);
    return __builtin_amdgcn_rcpf(1.f + e);
}
static __device__ __forceinline__ float tanh_f(float x) {
    x = fminf(fmaxf(x, -15.f), 15.f);
    float e = __expf(2.f * x);
    return 1.f - 2.f * __builtin_amdgcn_rcpf(1.f + e);
}

// ---------------- prep: fused weights + bias + x->bf16 + hbuf init ----------
__global__ __launch_bounds__(256) void prep_kernel(
    const float* __restrict__ x,
    const float* __restrict__ Wf, const float* __restrict__ bf_,
    const float* __restrict__ Wi, const float* __restrict__ bi_,
    const float* __restrict__ Wg, const float* __restrict__ bg_,
    const float* __restrict__ Wo, const float* __restrict__ bo_,
    const float* __restrict__ Mf, const float* __restrict__ mbf_,
    const float* __restrict__ Mi, const float* __restrict__ mbi_,
    const float* __restrict__ Mg, const float* __restrict__ mbg_,
    const float* __restrict__ Mo, const float* __restrict__ mbo_,
    unsigned short* __restrict__ Khp,   // packed [32][4][16][64][8] bf16
    unsigned short* __restrict__ Kxp,   // packed [32][4][8][64][8]  bf16
    float* __restrict__ bias_out,       // [2048]
    unsigned short* __restrict__ xbf,   // [512*64*256] bf16
    unsigned short* __restrict__ hb)    // [4][64*512]: buf0=0, buf1..3=sentinel
{
    const float* Ws[4] = {Wf, Wi, Wg, Wo};
    const float* Ms[4] = {Mf, Mi, Mg, Mo};
    const float* bs[4] = {bf_, bi_, bg_, bo_};
    const float* mbs[4] = {mbf_, mbi_, mbg_, mbo_};
    const long long NKH = 512LL * 2048;
    const long long NKX = 256LL * 2048;
    const long long NB_ = 2048;
    const long long NX = 512LL * 64 * 256;
    const long long NHB = 4LL * 32768;
    const long long total = NKH + NKX + NB_ + NX + NHB;
    for (long long id = (long long)blockIdx.x * blockDim.x + threadIdx.x; id < total;
         id += (long long)gridDim.x * blockDim.x) {
        if (id < NKH) {
            int i = (int)id;
            int k = i >> 11, scol = i & 2047;
            int n = scol >> 9, c = scol & 511;
            const float* W = Ws[n]; const float* M = Ms[n];
            float acc = 0.f;
            #pragma unroll 8
            for (int q = 0; q < 64; ++q) acc = fmaf(W[(256 + k) * 64 + q], M[q * 512 + c], acc);
            int blk = c >> 4, jj = c & 15, kc = k >> 5;
            int l = (((k >> 3) & 3) << 4) | jj, j = k & 7;
            Khp[((((blk * 4 + n) * 16 + kc) * 64 + l) << 3) + j] = f2bf(acc);
        } else if (id < NKH + NKX) {
            int i = (int)(id - NKH);
            int k = i >> 11, scol = i & 2047;
            int n = scol >> 9, c = scol & 511;
            const float* W = Ws[n]; const float* M = Ms[n];
            float acc = 0.f;
            #pragma unroll 8
            for (int q = 0; q < 64; ++q) acc = fmaf(W[k * 64 + q], M[q * 512 + c], acc);
            int blk = c >> 4, jj = c & 15, kc = k >> 5;
            int l = (((k >> 3) & 3) << 4) | jj, j = k & 7;
            Kxp[((((blk * 4 + n) * 8 + kc) * 64 + l) << 3) + j] = f2bf(acc);
        } else if (id < NKH + NKX + NB_) {
            int scol = (int)(id - NKH - NKX);
            int n = scol >> 9, c = scol & 511;
            const float* M = Ms[n];
            float acc = mbs[n][c];
            #pragma unroll 8
            for (int q = 0; q < 64; ++q) acc = fmaf(bs[n][q], M[q * 512 + c], acc);
            bias_out[scol] = acc;
        } else if (id < NKH + NKX + NB_ + NX) {
            long long e = id - NKH - NKX - NB_;
            xbf[e] = f2bf(x[e]);
        } else {
            int e = (int)(id - NKH - NKX - NB_ - NX);
            hb[e] = (e < 32768) ? (unsigned short)0 : (unsigned short)0x7FC0;
        }
    }
}

// h chunk load: MALL-coherent (bypass L1+L2); early-clobber dest so the
// output can never alias the shared address register hr
#define HLOAD(i, off_) \
    asm volatile("global_load_dwordx4 %0, %1, off offset:" #off_ " sc0 sc1" \
                 : "=&v"(hfrag[i]) : "v"(hr))

// ---------------- persistent recurrence kernel ----------------
// 128 blocks x 64 threads (1 wave/block, 1 block/CU via 96KB LDS).
// Block bid: w = bid>>5 (rows [16w,16w+16)), slot = bid&31 (cols
// [slot*16,slot*16+16)). Domain w is an independent sync group of 32 waves.
__global__ __launch_bounds__(64, 1) void qlstm_persist(
    const unsigned short* __restrict__ xbf,
    const unsigned short* __restrict__ Khp,
    const unsigned short* __restrict__ Kxp,
    const float* __restrict__ bias,
    float* __restrict__ out,
    unsigned short* hbuf)        // [4][64*512] bf16 rotation
{
    extern __shared__ unsigned short smem[];
    unsigned short* lKh = smem;           // [4][16][64][8] = 64 KB
    unsigned short* lKx = smem + 32768;   // [4][8][64][8]  = 32 KB
    const int tid = threadIdx.x;
    const int slot = blockIdx.x & 31, w = blockIdx.x >> 5;
    const int lane = tid;

    // stage K slices into LDS (once; 1 wave does 96 KB)
    {
        const uint4* src = (const uint4*)(Khp + (size_t)slot * 32768);
        uint4* dst = (uint4*)lKh;
        for (int i = tid; i < 4096; i += 64) dst[i] = src[i];
        const uint4* src2 = (const uint4*)(Kxp + (size_t)slot * 16384);
        uint4* dst2 = (uint4*)lKx;
        for (int i = tid; i < 2048; i += 64) dst2[i] = src2[i];
    }
    __syncthreads();

    const int jj = lane & 15, lhi = lane >> 4;
    const int hcol = slot * 16 + jj;
    const int row0 = w * 16;
    const int browbase = row0 + lhi * 4;

    float bias_v[4];
    #pragma unroll
    for (int n = 0; n < 4; ++n) bias_v[n] = bias[n * 512 + hcol];
    float c_state[4] = {0.f, 0.f, 0.f, 0.f};

    // x fragments for t=0
    s16x8 xfrag[8];
    {
        const unsigned short* xr = xbf + (long long)(row0 + jj) * 256 + lhi * 8;
        #pragma unroll
        for (int kc = 0; kc < 8; ++kc) xfrag[kc] = *(const s16x8*)(xr + kc * 32);
    }

    for (int t = 0; t < 512; ++t) {
        const unsigned short* hcur = hbuf + (t & 3) * 32768;
        unsigned short* hnext = hbuf + ((t + 1) & 3) * 32768;
        unsigned short* hpois = hbuf + ((t + 3) & 3) * 32768;   // == (t-1) mod 4

        // ---- x part (independent of h): acc = bias + x_t @ Kx (Kx from LDS) ----
        f32x4 acc[4];
        #pragma unroll
        for (int n = 0; n < 4; ++n) {
            f32x4 b0 = {bias_v[n], bias_v[n], bias_v[n], bias_v[n]};
            acc[n] = b0;
        }
        #pragma unroll
        for (int kc = 0; kc < 8; ++kc) {
            #pragma unroll
            for (int n = 0; n < 4; ++n) {
                s16x8 b = *(const s16x8*)(lKx + (((n * 8 + kc) * 64 + lane) << 3));
                acc[n] = __builtin_amdgcn_mfma_f32_16x16x32_bf16(xfrag[kc], b, acc[n], 0, 0, 0);
            }
        }

        // prefetch next step's x fragments (plain cached; completes under poll)
        if (t < 511) {
            const unsigned short* xr = xbf + ((long long)(t + 1) * 64 + row0 + jj) * 256 + lhi * 8;
            #pragma unroll
            for (int kc = 0; kc < 8; ++kc) xfrag[kc] = *(const s16x8*)(xr + kc * 32);
        }

        // ---- poll directly on h data (R5 full-sweep, proven) ----
        s16x8 hfrag[16];
        const unsigned short* hr = hcur + (row0 + jj) * 512 + lhi * 8;
        int sweeps = 0;
        for (;;) {
            HLOAD(0, 0);    HLOAD(1, 64);   HLOAD(2, 128);  HLOAD(3, 192);
            HLOAD(4, 256);  HLOAD(5, 320);  HLOAD(6, 384);  HLOAD(7, 448);
            HLOAD(8, 512);  HLOAD(9, 576);  HLOAD(10, 640); HLOAD(11, 704);
            HLOAD(12, 768); HLOAD(13, 832); HLOAD(14, 896); HLOAD(15, 960);
            asm volatile("s_waitcnt vmcnt(0)" ::: "memory");
            __builtin_amdgcn_sched_barrier(0);
            int bad = 0;
            #pragma unroll
            for (int kc = 0; kc < 16; ++kc)
                bad |= (hfrag[kc][0] == SENT16) | (hfrag[kc][4] == SENT16);
            if (!__any(bad) || ++sweeps > 16384) break;   // bound: never hang
        }
        __builtin_amdgcn_sched_barrier(0);

        // ---- h part: acc += h(t) @ Kh (Kh from LDS) ----
        #pragma unroll
        for (int kc = 0; kc < 16; ++kc) {
            #pragma unroll
            for (int n = 0; n < 4; ++n) {
                s16x8 b = *(const s16x8*)(lKh + (((n * 16 + kc) * 64 + lane) << 3));
                acc[n] = __builtin_amdgcn_mfma_f32_16x16x32_bf16(hfrag[kc], b, acc[n], 0, 0, 0);
            }
        }

        // ---- gates + state update; h data stores (atomic 8B, sc0 sc1) ----
        float hv[4], cv[4];
        #pragma unroll
        for (int r = 0; r < 4; ++r) {
            float fv = sigmoid_f(acc[0][r]);
            float iv = sigmoid_f(acc[1][r]);
            float gv = tanh_f(acc[2][r]);
            float ov = sigmoid_f(acc[3][r]);
            float c = fmaf(fv, c_state[r], iv * gv);
            c_state[r] = c;
            float h = ov * tanh_f(c);
            hv[r] = h; cv[r] = c;
            unsigned int myb = f2bf(h);
            unsigned int o1 = (unsigned int)__shfl_xor((int)myb, 1, 64);
            unsigned int b01 = (myb & 0xFFFFu) | (o1 << 16);            // even jj
            unsigned long long o2 =
                (unsigned long long)(unsigned int)__shfl_xor((int)b01, 2, 64);
            unsigned long long q = (unsigned long long)b01 | (o2 << 32); // jj%4==0
            if ((jj & 3) == 0) {
                unsigned long long* ha =
                    (unsigned long long*)(hnext + (browbase + r) * 512 + slot * 16 + jj);
                asm volatile("global_store_dwordx2 %0, %1, off sc0 sc1"
                             :: "v"(ha), "v"(q) : "memory");
            }
        }

        // ---- re-poison the buffer consumed at step t-1 (own write tile).
        // Poll success at t proves all domain-w peers finished reading it;
        // next data write to it is at t+2; drains at the next poll.
        {
            unsigned long long s64 = 0x7FC07FC07FC07FC0ull;
            unsigned long long* pa = (unsigned long long*)
                (hpois + (row0 + (lane >> 2)) * 512 + slot * 16 + (lane & 3) * 4);
            asm volatile("global_store_dwordx2 %0, %1, off sc0 sc1"
                         :: "v"(pa), "v"(s64) : "memory");
        }

        // ---- out stores off the critical path (plain cached) ----
        float* outt = out + (long long)t * 32768;
        #pragma unroll
        for (int r = 0; r < 4; ++r) {
            const int brow = browbase + r;
            outt[brow * 512 + hcol] = hv[r];
            if (t == 511) {
                out[16777216 + brow * 512 + hcol] = hv[r];   // hT
                out[16809984 + brow * 512 + hcol] = cv[r];   // cT
            }
        }
    }
}

extern "C" void kernel_launch(void* const* d_in, const int* in_sizes, int n_in,
                              void* d_out, int out_size, void* d_ws, size_t ws_size,
                              hipStream_t stream) {
    const float* x   = (const float*)d_in[0];
    const float* Wf  = (const float*)d_in[1];  const float* bf_  = (const float*)d_in[2];
    const float* Wi  = (const float*)d_in[3];  const float* bi_  = (const float*)d_in[4];
    const float* Wg  = (const float*)d_in[5];  const float* bg_  = (const float*)d_in[6];
    const float* Wo  = (const float*)d_in[7];  const float* bo_  = (const float*)d_in[8];
    const float* Mf  = (const float*)d_in[9];  const float* mbf_ = (const float*)d_in[10];
    const float* Mi  = (const float*)d_in[11]; const float* mbi_ = (const float*)d_in[12];
    const float* Mg  = (const float*)d_in[13]; const float* mbg_ = (const float*)d_in[14];
    const float* Mo  = (const float*)d_in[15]; const float* mbo_ = (const float*)d_in[16];
    float* outp = (float*)d_out;

    char* ws = (char*)d_ws;
    unsigned short* xbf  = (unsigned short*)(ws);                    // 16,777,216 B
    unsigned short* Khp  = (unsigned short*)(ws + 16777216);         //  2,097,152 B
    unsigned short* Kxp  = (unsigned short*)(ws + 18874368);         //  1,048,576 B
    float*          bias = (float*)        (ws + 19922944);         //      8,192 B
    unsigned short* hbuf = (unsigned short*)(ws + 19931136);         //    262,144 B (4 bufs)
    if (ws_size < 20193280) return;

    // prep re-initializes ALL workspace state every call (graph-replay safe):
    // hbuf buf0 = h_0 = 0, buf1..3 = sentinel.
    prep_kernel<<<4096, 256, 0, stream>>>(
        x, Wf, bf_, Wi, bi_, Wg, bg_, Wo, bo_,
        Mf, mbf_, Mi, mbi_, Mg, mbg_, Mo, mbo_,
        Khp, Kxp, bias, xbf, hbuf);

    // 96 KB dynamic LDS (forces 1 block/CU -> each wave owns its CU)
    hipFuncSetAttribute((const void*)qlstm_persist,
                        hipFuncAttributeMaxDynamicSharedMemorySize, 98304);

    const unsigned short* xbf_c = xbf;
    const unsigned short* Khp_c = Khp;
    const unsigned short* Kxp_c = Kxp;
    const float* bias_c = bias;
    float* out_c = outp;
    unsigned short* hbuf_c = hbuf;
    void* args[] = {(void*)&xbf_c, (void*)&Khp_c, (void*)&Kxp_c, (void*)&bias_c,
                    (void*)&out_c, (void*)&hbuf_c};
    // 128 blocks x 64 threads (1 wave each), 1 block/CU
    hipLaunchCooperativeKernel((const void*)qlstm_persist, dim3(128), dim3(64),
                               args, 98304, stream);
}